// Round 9
// baseline (316.725 us; speedup 1.0000x reference)
//
#include <hip/hip_runtime.h>

#define N 4096            // row length
#define NEG_BIG -9999999.9f
#define CAP 16            // candidate slots (register-resident in Newton)

typedef float floatx4 __attribute__((ext_vector_type(4)));

// One row per 1024-thread block (16 waves, 4 elems/lane).
// Memory shape is r8's (proven: VGPR 20, 64 loads in flight per CU): exactly
// 2 coalesced float4 loads per lane issued back-to-back, one store.
// Fix vs r8: Newton ran redundantly on ALL 16 waves -> VALUBusy 66%, VALU
// time rivaled memory time. Now only wave 0 runs the register-resident
// candidate Newton (~500 VALU inst on one wave, ~10x less per row) and
// broadcasts tau via LDS. Other waves idle briefly at the barrier; the
// second resident block's loads cover the gap.
// tau via Newton on the candidate set {z > rmax-1} (provable superset of the
// sparsemax support: sum_support(z-tau)=1 => tau >= rmax-1; excluded elems
// contribute exactly 0 to f(u) for all u >= -1 -> bit-identical result).
__global__ __launch_bounds__(1024)
void sparsemax_kernel(const float* __restrict__ x,
                      const float* __restrict__ m,
                      float* __restrict__ out) {
    const int tid  = threadIdx.x;          // 0..1023 = float4 index in row
    const int lane = tid & 63;
    const int wid  = tid >> 6;             // 0..15
    const int row  = blockIdx.x;

    __shared__ float  smax[16];
    __shared__ float  cand[CAP];
    __shared__ float  su;                  // broadcast Newton result
    __shared__ float2 sparts[2][16];       // fallback partials
    __shared__ int    cnt;
    if (tid == 0) cnt = 0;

    const float4* __restrict__ xr = (const float4*)x + (size_t)row * (N / 4);
    const float4* __restrict__ mr = (const float4*)m + (size_t)row * (N / 4);
    floatx4* __restrict__ outr    = (floatx4*)out + (size_t)row * (N / 4);

    // ---- Two loads, issued together (the allocator can't serialize this) --
    float4 xv = xr[tid];
    float4 mv = mr[tid];

    // z = (mask ? x : NEG_BIG) * 2   (/(1-TEMP), TEMP=0.5)
    float z[4];
    z[0] = (mv.x != 0.0f ? xv.x : NEG_BIG) * 2.0f;
    z[1] = (mv.y != 0.0f ? xv.y : NEG_BIG) * 2.0f;
    z[2] = (mv.z != 0.0f ? xv.z : NEG_BIG) * 2.0f;
    z[3] = (mv.w != 0.0f ? xv.w : NEG_BIG) * 2.0f;

    // ---- Block max: wave butterfly, then 16 broadcast LDS reads ----
    float wmax = fmaxf(fmaxf(z[0], z[1]), fmaxf(z[2], z[3]));
#pragma unroll
    for (int k = 32; k >= 1; k >>= 1)
        wmax = fmaxf(wmax, __shfl_xor(wmax, k, 64));
    if (lane == 0) smax[wid] = wmax;
    __syncthreads();                       // smax + cnt=0 visible
    float rmax = smax[0];
#pragma unroll
    for (int w = 1; w < 16; ++w) rmax = fmaxf(rmax, smax[w]);

    // ---- Candidate collection: w = z - rmax, admit w > -1 ----
    const float thr0 = rmax - 1.0f;
#pragma unroll
    for (int i = 0; i < 4; ++i) {
        if (z[i] > thr0) {
            int idx = atomicAdd(&cnt, 1);
            if (idx < CAP) cand[idx] = z[i] - rmax;
        }
    }
    __syncthreads();                       // appends visible
    const int K = cnt;                     // block-uniform

    // ---- Newton for u (tau = rmax + u), u0 = -1, monotone increasing ----
    float u;
    if (K <= CAP) {
        if (wid == 0) {
            // Register-resident Newton on wave 0 only (~500 VALU inst).
            float cr[CAP];
#pragma unroll
            for (int j = 0; j < CAP; ++j)
                cr[j] = (j < K) ? cand[j] : -3.0e38f;
            float uu = -1.0f;
            for (int it = 0; it < 32; ++it) {
                float s = 0.0f, c = 0.0f;
#pragma unroll
                for (int j = 0; j < CAP; ++j) {
                    float v = cr[j] - uu;
                    if (v > 0.0f) { s += v; c += 1.0f; }
                }
                float un = uu + (s - 1.0f) / c;  // c >= 1 while uu <= u*
                if (!(un > uu)) break;           // exact fixed point
                uu = un;
            }
            if (lane == 0) su = uu;
        }
        __syncthreads();                   // su visible
        u = su;
    } else {
        // Rare fallback (e.g. all-masked row: all w==0 admitted). K is
        // block-uniform -> all threads here; u sequence identical on every
        // thread -> barriers and break are block-uniform.
        u = -1.0f;
        int parity = 0;
        for (int it = 0; it < 32; ++it) {
            float s = 0.0f, c = 0.0f;
#pragma unroll
            for (int i = 0; i < 4; ++i) {
                float v = (z[i] - rmax) - u;
                if (v > 0.0f) { s += v; c += 1.0f; }
            }
#pragma unroll
            for (int k = 32; k >= 1; k >>= 1) {
                s += __shfl_xor(s, k, 64);
                c += __shfl_xor(c, k, 64);
            }
            if (lane == 0) sparts[parity][wid] = make_float2(s, c);
            __syncthreads();
            float S = 0.0f, C = 0.0f;
#pragma unroll
            for (int w = 0; w < 16; ++w) {
                float2 p = sparts[parity][w];
                S += p.x; C += p.y;
            }
            float un = u + (S - 1.0f) / C;
            parity ^= 1;
            if (!(un > u)) break;
            u = un;
        }
    }

    // ---- Output; masked entries hit the relu floor (z-tau << 0) ----
    // All-masked row: reference multiplies by mask -> exact zeros via live.
    const float live = (rmax == NEG_BIG * 2.0f) ? 0.0f : 1.0f;
    const float thr  = rmax + u;           // = tau

    floatx4 o;
    o.x = fmaxf(z[0] - thr, 0.0f) * live;
    o.y = fmaxf(z[1] - thr, 0.0f) * live;
    o.z = fmaxf(z[2] - thr, 0.0f) * live;
    o.w = fmaxf(z[3] - thr, 0.0f) * live;
    __builtin_nontemporal_store(o, outr + tid);
}

extern "C" void kernel_launch(void* const* d_in, const int* in_sizes, int n_in,
                              void* d_out, int out_size, void* d_ws, size_t ws_size,
                              hipStream_t stream) {
    const float* x = (const float*)d_in[0];
    const float* m = (const float*)d_in[1];
    float* out = (float*)d_out;
    const int rows = in_sizes[0] / N;      // 8192
    sparsemax_kernel<<<rows, 1024, 0, stream>>>(x, m, out);
}